// Round 7
// baseline (298.925 us; speedup 1.0000x reference)
//
#include <hip/hip_runtime.h>
#include <hip/hip_bf16.h>

// GCN forward, MI355X. Round 7: dispatch-count + traffic trim of the R6
// de-fused structure.
//   memset(deg|pooled|cnt|done)   [one region]
//   cvt_we  : W->bf16 canonical (W1..W4 fragment-major) | batch->i32 |
//             degree count straight from raw edges (no src/dst copies)
//   scan1, scan23 : hierarchical scan -> row_ptr / cursor / dinv
//   fill    : packed uint2 CSR (src, coef), reads raw edges directly
//   gemm1   : X @ W1 via MFMA straight from raw x (fp32 or bf16)
//   3x (agg<F> standalone [16B/lane gather, max occupancy] ->
//       gemm<FIN,FOUT> [LDS-free, fragment-major W])
//   agg_pool_final: last-layer gather + LDS pool -> global atomics ->
//             last-arriving block computes the 64x10 output (done-counter)
//
// Lessons: R5 — fused agg+MFMA tiles crater occupancy (13%) and expose L3
// gather latency; keep agg standalone at 32 waves/CU. R6 — per-dispatch gap
// ~5us dominates over traffic; cut dispatches.
//
// MFMA 16x16x32_bf16 layouts (verified): A[m=l&15][k=(l>>4)*8+j] (k-contig);
// B frag f at Wf[f*1024 + l*16..+16] = B[kb*32+(l>>4)*8+j][ct*16+(l&15)],
// f=ct*KB+kb; C/D col=l&15, row=(l>>4)*4+reg.

#define N_GRAPHS 64
#define N_CLASSES 10

typedef short bf8_t __attribute__((ext_vector_type(8)));
typedef float f4_t  __attribute__((ext_vector_type(4)));

__device__ __forceinline__ float b2f(unsigned int u) {
  return __uint_as_float(u << 16);
}
__device__ __forceinline__ unsigned short f2b(float f) {
  unsigned int x = __float_as_uint(f);
  x += 0x7fffu + ((x >> 16) & 1u);   // RNE (finite values only)
  return (unsigned short)(x >> 16);
}

// Per-block dtype detect; call with all 256 threads pre-divergence.
__device__ __forceinline__ void block_detect(const unsigned int* __restrict__ xraw,
    const unsigned int* __restrict__ eraw, int* f32, int* i64) {
  __shared__ int c_bf, c_nz;
  if (threadIdx.x == 0) { c_bf = 0; c_nz = 0; }
  __syncthreads();
  unsigned int d = xraw[threadIdx.x & 255];
  int e = (int)(((d & 0xffffu) >> 7) & 0xff);
  if (e >= 100 && e <= 140) atomicAdd(&c_bf, 1);
  if (eraw && threadIdx.x < 64 && eraw[2 * threadIdx.x + 1] != 0u) atomicAdd(&c_nz, 1);
  __syncthreads();
  *f32 = (c_bf < 150) ? 1 : 0;
  if (i64) *i64 = (c_nz == 0) ? 1 : 0;
}

struct WPtrs { const void* p[10]; };
static constexpr int WSEG[10] = {16384, 128, 8192, 64, 2048, 32, 512, 16, 160, 10};
static constexpr int WTOTAL   = 27546;
static constexpr int WOFF[10] = {0, 16384, 16512, 24704, 24768, 26816, 26848, 27360, 27376, 27536};

// blocks [0,BW): weights; [BW,BW+BB): batch; rest: degree count from eraw.
__global__ __launch_bounds__(256) void cvt_we_kernel(
    const unsigned int* __restrict__ xraw, WPtrs wp, unsigned short* __restrict__ wc,
    const int* __restrict__ braw, int* __restrict__ b32,
    const int* __restrict__ eraw, int* __restrict__ deg,
    int BW, int BB, int n, int E) {
  int f32, i64;
  block_detect(xraw, (const unsigned int*)eraw, &f32, &i64);
  const int bid = blockIdx.x;
  if (bid < BW) {
    int i = bid * 256 + threadIdx.x;
    if (i >= WTOTAL) return;
    int off = i, s = 0;
    #pragma unroll
    for (int t = 0; t < 10; ++t) {
      if (s == 0 && off >= WSEG[t]) { off -= WSEG[t]; } else if (s == 0) { s = t + 1; }
    }
    s -= 1;
    int soff = off;
    if ((s & 1) == 0 && s <= 6) {           // W1..W4 -> fragment-major
      int KB, FOUT;
      if (s == 0)      { KB = 4; FOUT = 128; }
      else if (s == 2) { KB = 4; FOUT = 64; }
      else if (s == 4) { KB = 2; FOUT = 32; }
      else             { KB = 1; FOUT = 16; }
      int j = off & 7, l = (off >> 3) & 63, f = off >> 9;
      int ct = f / KB, kb = f - ct * KB;
      int k = kb * 32 + ((l >> 4) << 3) + j;
      int nn = ct * 16 + (l & 15);
      soff = k * FOUT + nn;
    }
    const void* p = wp.p[s];
    wc[WOFF[s] + off] = f32 ? f2b(((const float*)p)[soff])
                            : ((const unsigned short*)p)[soff];
  } else if (bid < BW + BB) {
    int i = (bid - BW) * 256 + threadIdx.x;
    if (i < n) b32[i] = i64 ? braw[2 * i] : braw[i];
  } else {
    int e = (bid - BW - BB) * 256 + threadIdx.x;
    if (e >= E) return;
    int d = i64 ? eraw[2 * (E + e)] : eraw[E + e];
    atomicAdd(&deg[d], 1);
  }
}

__device__ __forceinline__ int block_incl_scan(int v, int* wave_sums) {
  const int lane = threadIdx.x & 63;
  const int wv = threadIdx.x >> 6;
  int x = v;
  #pragma unroll
  for (int off = 1; off < 64; off <<= 1) {
    int y = __shfl_up(x, off, 64);
    if (lane >= off) x += y;
  }
  if (lane == 63) wave_sums[wv] = x;
  __syncthreads();
  int wbase = 0;
  for (int w = 0; w < wv; ++w) wbase += wave_sums[w];
  return x + wbase;
}

__global__ __launch_bounds__(256) void scan1_kernel(const int* __restrict__ deg,
    int* __restrict__ partials, int n) {
  __shared__ int ws[4];
  int i = blockIdx.x * 256 + threadIdx.x;
  int v = (i < n) ? deg[i] : 0;
  int incl = block_incl_scan(v, ws);
  if (threadIdx.x == 255) partials[blockIdx.x] = incl;
}

__global__ __launch_bounds__(256) void scan23_kernel(const int* __restrict__ deg,
    const int* __restrict__ partials, int* __restrict__ row_ptr, int* __restrict__ cursor,
    float* __restrict__ dinv, int n, int nb) {
  __shared__ int ws[4];
  __shared__ int s_red[4];
  __shared__ int s_base;
  int i = blockIdx.x * 256 + threadIdx.x;
  int v = (i < n) ? deg[i] : 0;
  int incl = block_incl_scan(v, ws);
  int pv = (threadIdx.x < blockIdx.x && threadIdx.x < nb) ? partials[threadIdx.x] : 0;
  #pragma unroll
  for (int off = 32; off; off >>= 1) pv += __shfl_xor(pv, off, 64);
  __syncthreads();
  if ((threadIdx.x & 63) == 0) s_red[threadIdx.x >> 6] = pv;
  __syncthreads();
  if (threadIdx.x == 0) s_base = s_red[0] + s_red[1] + s_red[2] + s_red[3];
  __syncthreads();
  int total = s_base + incl;
  if (i < n) {
    row_ptr[i + 1] = total;
    cursor[i] = total - v;
    dinv[i] = rsqrtf((float)v + 1.0f);
  }
  if (i == 0) row_ptr[0] = 0;
}

// Packed CSR fill, reading raw edges directly (dtype-strided).
__global__ __launch_bounds__(256) void fill_kernel(const int* __restrict__ eraw,
    const unsigned int* __restrict__ xraw,
    int* __restrict__ cursor, const float* __restrict__ dinv,
    uint2* __restrict__ csr, int E) {
  int f32, i64;
  block_detect(xraw, (const unsigned int*)eraw, &f32, &i64);
  int e = blockIdx.x * 256 + threadIdx.x;
  if (e < E) {
    int s, d;
    if (i64) { s = eraw[2 * e]; d = eraw[2 * (E + e)]; }
    else     { s = eraw[e];     d = eraw[E + e]; }
    int pos = atomicAdd(&cursor[d], 1);
    uint2 v;
    v.x = (unsigned int)s;
    v.y = __float_as_uint(dinv[s] * dinv[d]);
    csr[pos] = v;
  }
}

// H = X @ W1 via MFMA; A-frags straight from raw x (fp32 or bf16).
__global__ __launch_bounds__(256) void gemm1_kernel(const unsigned int* __restrict__ xraw,
    const unsigned short* __restrict__ Wf, unsigned short* __restrict__ H, int n) {
  int f32;
  block_detect(xraw, nullptr, &f32, nullptr);
  const int l = threadIdx.x & 63;
  const int r16 = l & 15, quad = l >> 4;
  const int m0 = (blockIdx.x * 4 + (threadIdx.x >> 6)) * 32;
  if (m0 >= n) return;
  bf8_t afrag[2][4];
  #pragma unroll
  for (int mt = 0; mt < 2; ++mt) {
    int node = m0 + mt * 16 + r16;
    int nc = node < n ? node : n - 1;
    if (f32) {
      const float* xp = (const float*)xraw + (size_t)nc * 128 + quad * 8;
      #pragma unroll
      for (int kb = 0; kb < 4; ++kb) {
        const float4* p4 = (const float4*)(xp + kb * 32);
        float4 u0 = p4[0], u1 = p4[1];
        bf8_t a;
        a[0] = (short)f2b(u0.x); a[1] = (short)f2b(u0.y);
        a[2] = (short)f2b(u0.z); a[3] = (short)f2b(u0.w);
        a[4] = (short)f2b(u1.x); a[5] = (short)f2b(u1.y);
        a[6] = (short)f2b(u1.z); a[7] = (short)f2b(u1.w);
        afrag[mt][kb] = a;
      }
    } else {
      const unsigned short* xp = (const unsigned short*)xraw + (size_t)nc * 128 + quad * 8;
      #pragma unroll
      for (int kb = 0; kb < 4; ++kb)
        afrag[mt][kb] = *(const bf8_t*)(xp + kb * 32);
    }
  }
  #pragma unroll
  for (int ct = 0; ct < 8; ++ct) {
    bf8_t bfrag[4];
    #pragma unroll
    for (int kb = 0; kb < 4; ++kb)
      bfrag[kb] = *(const bf8_t*)(Wf + ((ct * 4 + kb) * 64 + l) * 8);
    #pragma unroll
    for (int mt = 0; mt < 2; ++mt) {
      f4_t acc = {0.f, 0.f, 0.f, 0.f};
      #pragma unroll
      for (int kb = 0; kb < 4; ++kb)
        acc = __builtin_amdgcn_mfma_f32_16x16x32_bf16(afrag[mt][kb], bfrag[kb], acc, 0, 0, 0);
      #pragma unroll
      for (int r = 0; r < 4; ++r) {
        int node = m0 + mt * 16 + quad * 4 + r;
        if (node < n)
          H[(size_t)node * 128 + ct * 16 + r16] = f2b(acc[r]);
      }
    }
  }
}

// Standalone GEMM: H[n,FOUT] = X[n,FIN] @ Wf (fragment-major). No LDS.
template<int FIN, int FOUT>
__global__ __launch_bounds__(256) void mfma_gemm_kernel(const unsigned short* __restrict__ X,
    const unsigned short* __restrict__ Wf, unsigned short* __restrict__ H, int n) {
  constexpr int KB = FIN / 32;
  constexpr int CT = FOUT / 16;
  const int l = threadIdx.x & 63;
  const int r16 = l & 15, quad = l >> 4;
  const int m0 = (blockIdx.x * 4 + (threadIdx.x >> 6)) * 32;
  if (m0 >= n) return;
  bf8_t afrag[2][KB];
  #pragma unroll
  for (int mt = 0; mt < 2; ++mt) {
    int node = m0 + mt * 16 + r16;
    int nc = node < n ? node : n - 1;
    const unsigned short* xp = X + (size_t)nc * FIN + quad * 8;
    #pragma unroll
    for (int kb = 0; kb < KB; ++kb)
      afrag[mt][kb] = *(const bf8_t*)(xp + kb * 32);
  }
  #pragma unroll
  for (int ct = 0; ct < CT; ++ct) {
    bf8_t bfrag[KB];
    #pragma unroll
    for (int kb = 0; kb < KB; ++kb)
      bfrag[kb] = *(const bf8_t*)(Wf + ((ct * KB + kb) * 64 + l) * 8);
    #pragma unroll
    for (int mt = 0; mt < 2; ++mt) {
      f4_t acc = {0.f, 0.f, 0.f, 0.f};
      #pragma unroll
      for (int kb = 0; kb < KB; ++kb)
        acc = __builtin_amdgcn_mfma_f32_16x16x32_bf16(afrag[mt][kb], bfrag[kb], acc, 0, 0, 0);
      #pragma unroll
      for (int r = 0; r < 4; ++r) {
        int node = m0 + mt * 16 + quad * 4 + r;
        if (node < n)
          H[(size_t)node * FOUT + ct * 16 + r16] = f2b(acc[r]);
      }
    }
  }
}

// Standalone agg: OUT[g,:] = relu(sum coef*H[src] + dinv^2*H[g] + bias).
template<int F>
__global__ __launch_bounds__(256) void agg_kernel(const unsigned short* __restrict__ H,
    const int* __restrict__ row_ptr, const uint2* __restrict__ csr,
    const float* __restrict__ dinv,
    const unsigned short* __restrict__ bias, unsigned short* __restrict__ OUT, int n) {
  constexpr int LPG = F / 8;
  constexpr int GPB = 256 / LPG;
  const int g = blockIdx.x * GPB + threadIdx.x / LPG;
  const int l = threadIdx.x % LPG;
  if (g >= n) return;
  const uint4* H4 = (const uint4*)H;
  float di = dinv[g];
  float c0 = di * di;
  uint4 hv = H4[(size_t)g * LPG + l];
  float a0 = b2f(hv.x & 0xffffu) * c0, a1 = b2f(hv.x >> 16) * c0;
  float a2 = b2f(hv.y & 0xffffu) * c0, a3 = b2f(hv.y >> 16) * c0;
  float a4 = b2f(hv.z & 0xffffu) * c0, a5 = b2f(hv.z >> 16) * c0;
  float a6 = b2f(hv.w & 0xffffu) * c0, a7 = b2f(hv.w >> 16) * c0;
  const int e0 = row_ptr[g], e1 = row_ptr[g + 1];
  for (int base = e0; base < e1; base += LPG) {
    int cnt = e1 - base < LPG ? e1 - base : LPG;
    uint2 my = csr[(base + l < e1) ? (base + l) : (e1 - 1)];
    for (int j = 0; j < cnt; ++j) {
      int s = __shfl((int)my.x, j, LPG);
      float c = __uint_as_float(__shfl((int)my.y, j, LPG));
      uint4 v = H4[(size_t)s * LPG + l];
      a0 = fmaf(b2f(v.x & 0xffffu), c, a0); a1 = fmaf(b2f(v.x >> 16), c, a1);
      a2 = fmaf(b2f(v.y & 0xffffu), c, a2); a3 = fmaf(b2f(v.y >> 16), c, a3);
      a4 = fmaf(b2f(v.z & 0xffffu), c, a4); a5 = fmaf(b2f(v.z >> 16), c, a5);
      a6 = fmaf(b2f(v.w & 0xffffu), c, a6); a7 = fmaf(b2f(v.w >> 16), c, a7);
    }
  }
  uint4 bb = ((const uint4*)bias)[l];
  a0 += b2f(bb.x & 0xffffu); a1 += b2f(bb.x >> 16);
  a2 += b2f(bb.y & 0xffffu); a3 += b2f(bb.y >> 16);
  a4 += b2f(bb.z & 0xffffu); a5 += b2f(bb.z >> 16);
  a6 += b2f(bb.w & 0xffffu); a7 += b2f(bb.w >> 16);
  a0 = fmaxf(a0, 0.f); a1 = fmaxf(a1, 0.f); a2 = fmaxf(a2, 0.f); a3 = fmaxf(a3, 0.f);
  a4 = fmaxf(a4, 0.f); a5 = fmaxf(a5, 0.f); a6 = fmaxf(a6, 0.f); a7 = fmaxf(a7, 0.f);
  uint4 o;
  o.x = (unsigned int)f2b(a0) | ((unsigned int)f2b(a1) << 16);
  o.y = (unsigned int)f2b(a2) | ((unsigned int)f2b(a3) << 16);
  o.z = (unsigned int)f2b(a4) | ((unsigned int)f2b(a5) << 16);
  o.w = (unsigned int)f2b(a6) | ((unsigned int)f2b(a7) << 16);
  ((uint4*)OUT)[(size_t)g * LPG + l] = o;
}

// Fused last-layer agg + mean-pool + (last block) final linear.
// 128 nodes/block, 2 lanes/node. No early returns (done-counter at end).
__global__ __launch_bounds__(256) void agg_pool_final_kernel(
    const unsigned short* __restrict__ Hin,
    const int* __restrict__ row_ptr, const uint2* __restrict__ csr,
    const float* __restrict__ dinv, const unsigned short* __restrict__ bias,
    const int* __restrict__ batch, float* __restrict__ pooled,
    float* __restrict__ cnt, int* __restrict__ done,
    const unsigned short* __restrict__ wc, void* __restrict__ out,
    const unsigned int* __restrict__ xraw, int n) {
  int f32;
  block_detect(xraw, nullptr, &f32, nullptr);
  __shared__ float acc[N_GRAPHS * 16];
  __shared__ float ccnt[N_GRAPHS];
  __shared__ int s_last;
  for (int i = threadIdx.x; i < N_GRAPHS * 16; i += 256) acc[i] = 0.f;
  if (threadIdx.x < N_GRAPHS) ccnt[threadIdx.x] = 0.f;
  __syncthreads();
  const int r = threadIdx.x >> 1, l = threadIdx.x & 1;
  const int g = blockIdx.x * 128 + r;
  if (g < n) {
    const uint4* H4 = (const uint4*)Hin;
    float di = dinv[g];
    float c0 = di * di;
    uint4 hv = H4[(size_t)g * 2 + l];
    float a0 = b2f(hv.x & 0xffffu) * c0, a1 = b2f(hv.x >> 16) * c0;
    float a2 = b2f(hv.y & 0xffffu) * c0, a3 = b2f(hv.y >> 16) * c0;
    float a4 = b2f(hv.z & 0xffffu) * c0, a5 = b2f(hv.z >> 16) * c0;
    float a6 = b2f(hv.w & 0xffffu) * c0, a7 = b2f(hv.w >> 16) * c0;
    const int e0 = row_ptr[g], e1 = row_ptr[g + 1];
    for (int base = e0; base < e1; base += 2) {
      int cnt2 = e1 - base < 2 ? e1 - base : 2;
      uint2 my = csr[(base + l < e1) ? (base + l) : (e1 - 1)];
      for (int j = 0; j < cnt2; ++j) {
        int s = __shfl((int)my.x, j, 2);
        float c = __uint_as_float(__shfl((int)my.y, j, 2));
        uint4 v = H4[(size_t)s * 2 + l];
        a0 = fmaf(b2f(v.x & 0xffffu), c, a0); a1 = fmaf(b2f(v.x >> 16), c, a1);
        a2 = fmaf(b2f(v.y & 0xffffu), c, a2); a3 = fmaf(b2f(v.y >> 16), c, a3);
        a4 = fmaf(b2f(v.z & 0xffffu), c, a4); a5 = fmaf(b2f(v.z >> 16), c, a5);
        a6 = fmaf(b2f(v.w & 0xffffu), c, a6); a7 = fmaf(b2f(v.w >> 16), c, a7);
      }
    }
    uint4 bb = ((const uint4*)bias)[l];
    a0 += b2f(bb.x & 0xffffu); a1 += b2f(bb.x >> 16);
    a2 += b2f(bb.y & 0xffffu); a3 += b2f(bb.y >> 16);
    a4 += b2f(bb.z & 0xffffu); a5 += b2f(bb.z >> 16);
    a6 += b2f(bb.w & 0xffffu); a7 += b2f(bb.w >> 16);
    a0 = fmaxf(a0, 0.f); a1 = fmaxf(a1, 0.f); a2 = fmaxf(a2, 0.f); a3 = fmaxf(a3, 0.f);
    a4 = fmaxf(a4, 0.f); a5 = fmaxf(a5, 0.f); a6 = fmaxf(a6, 0.f); a7 = fmaxf(a7, 0.f);
    int gb = batch[g];
    float* ap = &acc[gb * 16 + l * 8];
    atomicAdd(ap + 0, a0); atomicAdd(ap + 1, a1);
    atomicAdd(ap + 2, a2); atomicAdd(ap + 3, a3);
    atomicAdd(ap + 4, a4); atomicAdd(ap + 5, a5);
    atomicAdd(ap + 6, a6); atomicAdd(ap + 7, a7);
    if (l == 0) atomicAdd(&ccnt[gb], 1.f);
  }
  __syncthreads();
  for (int i = threadIdx.x; i < N_GRAPHS * 16; i += 256)
    if (acc[i] != 0.f) atomicAdd(&pooled[i], acc[i]);
  if (threadIdx.x < N_GRAPHS && ccnt[threadIdx.x] != 0.f)
    atomicAdd(&cnt[threadIdx.x], ccnt[threadIdx.x]);
  // ---- completion counter: last block computes the final linear ----
  if (threadIdx.x == 0) {
    __threadfence();
    int old = atomicAdd(done, 1);
    s_last = (old == (int)gridDim.x - 1) ? 1 : 0;
  }
  __syncthreads();
  if (s_last) {
    __threadfence();
    const unsigned short* Wlin = wc + WOFF[8];
    const unsigned short* blin = wc + WOFF[9];
    for (int id = threadIdx.x; id < N_GRAPHS * N_CLASSES; id += 256) {
      int gg = id / N_CLASSES, c = id - gg * N_CLASSES;
      // coherent reads of other blocks' atomics via atomic RMW (+0)
      float cg = atomicAdd(&cnt[gg], 0.0f);
      float inv = 1.0f / fmaxf(cg, 1.0f);
      float a = b2f(blin[c]);
      #pragma unroll
      for (int f = 0; f < 16; ++f) {
        float pf = atomicAdd(&pooled[gg * 16 + f], 0.0f);
        a = fmaf(pf * inv, b2f(Wlin[f * N_CLASSES + c]), a);
      }
      if (f32) ((float*)out)[id] = a;
      else     ((unsigned short*)out)[id] = f2b(a);
    }
  }
}

extern "C" void kernel_launch(void* const* d_in, const int* in_sizes, int n_in,
                              void* d_out, int out_size, void* d_ws, size_t ws_size,
                              hipStream_t stream) {
  const unsigned int* xraw = (const unsigned int*)d_in[0];
  const int* eraw          = (const int*)d_in[1];
  const int* braw          = (const int*)d_in[2];

  const int N = in_sizes[2];
  const int E = in_sizes[1] / 2;

  char* p = (char*)d_ws;
  auto alloc = [&](size_t bytes) -> void* {
    void* r = (void*)p;
    p += (bytes + 255) & ~(size_t)255;
    return r;
  };
  // zero region: deg | pooled | cnt | done  (single memset)
  char*  zbase    = (char*) alloc((size_t)N * 4 + 8192);
  int*   deg      = (int*)  zbase;
  float* pooled   = (float*)(zbase + (size_t)N * 4);
  float* cntf     = pooled + N_GRAPHS * 16;
  int*   done     = (int*)(cntf + N_GRAPHS);
  const size_t zbytes = (size_t)N * 4 + (N_GRAPHS * 16 + N_GRAPHS + 1) * 4;

  int*   partials = (int*)  alloc(1024);
  int*   row_ptr  = (int*)  alloc((size_t)(N + 1) * 4);
  int*   cursor   = (int*)  alloc((size_t)N * 4);
  float* dinv     = (float*)alloc((size_t)N * 4);
  int*   batch32  = (int*)  alloc((size_t)N * 4);
  uint2* csr      = (uint2*)alloc((size_t)E * 8);
  unsigned short* wcan  = (unsigned short*)alloc((size_t)WTOTAL * 2);
  unsigned short* hbufA = (unsigned short*)alloc((size_t)N * 128 * 2);
  unsigned short* hbufB = (unsigned short*)alloc((size_t)N * 128 * 2);

  hipMemsetAsync(zbase, 0, zbytes, stream);

  WPtrs wp;
  for (int i = 0; i < 10; ++i) wp.p[i] = d_in[3 + i];

  const int BW = (WTOTAL + 255) / 256;
  const int BB = (N + 255) / 256;
  const int BE = (E + 255) / 256;
  cvt_we_kernel<<<BW + BB + BE, 256, 0, stream>>>(xraw, wp, wcan, braw, batch32,
      eraw, deg, BW, BB, N, E);

  const int nb = (N + 255) / 256;
  scan1_kernel<<<nb, 256, 0, stream>>>(deg, partials, N);
  scan23_kernel<<<nb, 256, 0, stream>>>(deg, partials, row_ptr, cursor, dinv, N, nb);
  fill_kernel<<<BE, 256, 0, stream>>>(eraw, xraw, cursor, dinv, csr, E);

  const unsigned short* W1 = wcan + WOFF[0];
  const unsigned short* b1 = wcan + WOFF[1];
  const unsigned short* W2 = wcan + WOFF[2];
  const unsigned short* b2 = wcan + WOFF[3];
  const unsigned short* W3 = wcan + WOFF[4];
  const unsigned short* b3 = wcan + WOFF[5];
  const unsigned short* W4 = wcan + WOFF[6];
  const unsigned short* b4 = wcan + WOFF[7];

  const int gblocks = ((N + 31) / 32 + 3) / 4;   // == ceil(N/128)
  const int tiles128 = (N + 127) / 128;

  gemm1_kernel<<<gblocks, 256, 0, stream>>>(xraw, W1, hbufA, N);
  agg_kernel<128><<<(N + 15) / 16, 256, 0, stream>>>(hbufA, row_ptr, csr, dinv, b1, hbufB, N);
  mfma_gemm_kernel<128, 64><<<gblocks, 256, 0, stream>>>(hbufB, W2, hbufA, N);
  agg_kernel<64><<<(N + 31) / 32, 256, 0, stream>>>(hbufA, row_ptr, csr, dinv, b2, hbufB, N);
  mfma_gemm_kernel<64, 32><<<gblocks, 256, 0, stream>>>(hbufB, W3, hbufA, N);
  agg_kernel<32><<<(N + 63) / 64, 256, 0, stream>>>(hbufA, row_ptr, csr, dinv, b3, hbufB, N);
  mfma_gemm_kernel<32, 16><<<gblocks, 256, 0, stream>>>(hbufB, W4, hbufA, N);
  agg_pool_final_kernel<<<tiles128, 256, 0, stream>>>(hbufA, row_ptr, csr, dinv, b4,
      batch32, pooled, cntf, done, wcan, d_out, xraw, N);
}

// Round 8
// 262.307 us; speedup vs baseline: 1.1396x; 1.1396x over previous
//
#include <hip/hip_runtime.h>
#include <hip/hip_bf16.h>

// GCN forward, MI355X. Round 8: R7 minus the device-fence regression, plus
// wide-LPG tail aggregation.
//   memset(deg|pooled|cnt)  [one region]
//   cvt_we  : W->bf16 canonical (W1..W4 fragment-major) | batch->i32 |
//             degree count straight from raw edges
//   scan1, scan23 : hierarchical scan -> row_ptr / cursor / dinv
//   fill    : packed uint2 CSR (src, coef), reads raw edges directly
//   gemm1   : X @ W1 via MFMA straight from raw x (fp32 or bf16)
//   3x (agg<F,LPG> standalone -> gemm<FIN,FOUT> [LDS-free, frag-major W])
//   agg_pool: last-layer gather (LPG=8) + LDS graph pool -> global atomics
//   final   : 64x16 @ 16x10 linear, dtype-dispatched store
//
// Lessons: R5 — fused agg+MFMA tiles crater occupancy; keep agg standalone.
// R7 — __threadfence per block = L2 writeback x391, +20us; never fence in
// wide grids. Agg chain = ceil(deg/LPG) dependent gather batches and grid =
// N*LPG/256: widen LPG for small F (chain down, occupancy up).
//
// MFMA 16x16x32_bf16 layouts (verified): A[m=l&15][k=(l>>4)*8+j] (k-contig);
// B frag f at Wf[f*1024 + l*16..+16] = B[kb*32+(l>>4)*8+j][ct*16+(l&15)],
// f=ct*KB+kb; C/D col=l&15, row=(l>>4)*4+reg.

#define N_GRAPHS 64
#define N_CLASSES 10

typedef short bf8_t __attribute__((ext_vector_type(8)));
typedef float f4_t  __attribute__((ext_vector_type(4)));

__device__ __forceinline__ float b2f(unsigned int u) {
  return __uint_as_float(u << 16);
}
__device__ __forceinline__ unsigned short f2b(float f) {
  unsigned int x = __float_as_uint(f);
  x += 0x7fffu + ((x >> 16) & 1u);   // RNE (finite values only)
  return (unsigned short)(x >> 16);
}

// Per-block dtype detect; call with all 256 threads pre-divergence.
__device__ __forceinline__ void block_detect(const unsigned int* __restrict__ xraw,
    const unsigned int* __restrict__ eraw, int* f32, int* i64) {
  __shared__ int c_bf, c_nz;
  if (threadIdx.x == 0) { c_bf = 0; c_nz = 0; }
  __syncthreads();
  unsigned int d = xraw[threadIdx.x & 255];
  int e = (int)(((d & 0xffffu) >> 7) & 0xff);
  if (e >= 100 && e <= 140) atomicAdd(&c_bf, 1);
  if (eraw && threadIdx.x < 64 && eraw[2 * threadIdx.x + 1] != 0u) atomicAdd(&c_nz, 1);
  __syncthreads();
  *f32 = (c_bf < 150) ? 1 : 0;
  if (i64) *i64 = (c_nz == 0) ? 1 : 0;
}

struct WPtrs { const void* p[10]; };
static constexpr int WSEG[10] = {16384, 128, 8192, 64, 2048, 32, 512, 16, 160, 10};
static constexpr int WTOTAL   = 27546;
static constexpr int WOFF[10] = {0, 16384, 16512, 24704, 24768, 26816, 26848, 27360, 27376, 27536};

// blocks [0,BW): weights; [BW,BW+BB): batch; rest: degree count from eraw.
__global__ __launch_bounds__(256) void cvt_we_kernel(
    const unsigned int* __restrict__ xraw, WPtrs wp, unsigned short* __restrict__ wc,
    const int* __restrict__ braw, int* __restrict__ b32,
    const int* __restrict__ eraw, int* __restrict__ deg,
    int BW, int BB, int n, int E) {
  int f32, i64;
  block_detect(xraw, (const unsigned int*)eraw, &f32, &i64);
  const int bid = blockIdx.x;
  if (bid < BW) {
    int i = bid * 256 + threadIdx.x;
    if (i >= WTOTAL) return;
    int off = i, s = 0;
    #pragma unroll
    for (int t = 0; t < 10; ++t) {
      if (s == 0 && off >= WSEG[t]) { off -= WSEG[t]; } else if (s == 0) { s = t + 1; }
    }
    s -= 1;
    int soff = off;
    if ((s & 1) == 0 && s <= 6) {           // W1..W4 -> fragment-major
      int KB, FOUT;
      if (s == 0)      { KB = 4; FOUT = 128; }
      else if (s == 2) { KB = 4; FOUT = 64; }
      else if (s == 4) { KB = 2; FOUT = 32; }
      else             { KB = 1; FOUT = 16; }
      int j = off & 7, l = (off >> 3) & 63, f = off >> 9;
      int ct = f / KB, kb = f - ct * KB;
      int k = kb * 32 + ((l >> 4) << 3) + j;
      int nn = ct * 16 + (l & 15);
      soff = k * FOUT + nn;
    }
    const void* p = wp.p[s];
    wc[WOFF[s] + off] = f32 ? f2b(((const float*)p)[soff])
                            : ((const unsigned short*)p)[soff];
  } else if (bid < BW + BB) {
    int i = (bid - BW) * 256 + threadIdx.x;
    if (i < n) b32[i] = i64 ? braw[2 * i] : braw[i];
  } else {
    int e = (bid - BW - BB) * 256 + threadIdx.x;
    if (e >= E) return;
    int d = i64 ? eraw[2 * (E + e)] : eraw[E + e];
    atomicAdd(&deg[d], 1);
  }
}

__device__ __forceinline__ int block_incl_scan(int v, int* wave_sums) {
  const int lane = threadIdx.x & 63;
  const int wv = threadIdx.x >> 6;
  int x = v;
  #pragma unroll
  for (int off = 1; off < 64; off <<= 1) {
    int y = __shfl_up(x, off, 64);
    if (lane >= off) x += y;
  }
  if (lane == 63) wave_sums[wv] = x;
  __syncthreads();
  int wbase = 0;
  for (int w = 0; w < wv; ++w) wbase += wave_sums[w];
  return x + wbase;
}

__global__ __launch_bounds__(256) void scan1_kernel(const int* __restrict__ deg,
    int* __restrict__ partials, int n) {
  __shared__ int ws[4];
  int i = blockIdx.x * 256 + threadIdx.x;
  int v = (i < n) ? deg[i] : 0;
  int incl = block_incl_scan(v, ws);
  if (threadIdx.x == 255) partials[blockIdx.x] = incl;
}

__global__ __launch_bounds__(256) void scan23_kernel(const int* __restrict__ deg,
    const int* __restrict__ partials, int* __restrict__ row_ptr, int* __restrict__ cursor,
    float* __restrict__ dinv, int n, int nb) {
  __shared__ int ws[4];
  __shared__ int s_red[4];
  __shared__ int s_base;
  int i = blockIdx.x * 256 + threadIdx.x;
  int v = (i < n) ? deg[i] : 0;
  int incl = block_incl_scan(v, ws);
  int pv = (threadIdx.x < blockIdx.x && threadIdx.x < nb) ? partials[threadIdx.x] : 0;
  #pragma unroll
  for (int off = 32; off; off >>= 1) pv += __shfl_xor(pv, off, 64);
  __syncthreads();
  if ((threadIdx.x & 63) == 0) s_red[threadIdx.x >> 6] = pv;
  __syncthreads();
  if (threadIdx.x == 0) s_base = s_red[0] + s_red[1] + s_red[2] + s_red[3];
  __syncthreads();
  int total = s_base + incl;
  if (i < n) {
    row_ptr[i + 1] = total;
    cursor[i] = total - v;
    dinv[i] = rsqrtf((float)v + 1.0f);
  }
  if (i == 0) row_ptr[0] = 0;
}

// Packed CSR fill, reading raw edges directly (dtype-strided).
__global__ __launch_bounds__(256) void fill_kernel(const int* __restrict__ eraw,
    const unsigned int* __restrict__ xraw,
    int* __restrict__ cursor, const float* __restrict__ dinv,
    uint2* __restrict__ csr, int E) {
  int f32, i64;
  block_detect(xraw, (const unsigned int*)eraw, &f32, &i64);
  int e = blockIdx.x * 256 + threadIdx.x;
  if (e < E) {
    int s, d;
    if (i64) { s = eraw[2 * e]; d = eraw[2 * (E + e)]; }
    else     { s = eraw[e];     d = eraw[E + e]; }
    int pos = atomicAdd(&cursor[d], 1);
    uint2 v;
    v.x = (unsigned int)s;
    v.y = __float_as_uint(dinv[s] * dinv[d]);
    csr[pos] = v;
  }
}

// H = X @ W1 via MFMA; A-frags straight from raw x (fp32 or bf16).
__global__ __launch_bounds__(256) void gemm1_kernel(const unsigned int* __restrict__ xraw,
    const unsigned short* __restrict__ Wf, unsigned short* __restrict__ H, int n) {
  int f32;
  block_detect(xraw, nullptr, &f32, nullptr);
  const int l = threadIdx.x & 63;
  const int r16 = l & 15, quad = l >> 4;
  const int m0 = (blockIdx.x * 4 + (threadIdx.x >> 6)) * 32;
  if (m0 >= n) return;
  bf8_t afrag[2][4];
  #pragma unroll
  for (int mt = 0; mt < 2; ++mt) {
    int node = m0 + mt * 16 + r16;
    int nc = node < n ? node : n - 1;
    if (f32) {
      const float* xp = (const float*)xraw + (size_t)nc * 128 + quad * 8;
      #pragma unroll
      for (int kb = 0; kb < 4; ++kb) {
        const float4* p4 = (const float4*)(xp + kb * 32);
        float4 u0 = p4[0], u1 = p4[1];
        bf8_t a;
        a[0] = (short)f2b(u0.x); a[1] = (short)f2b(u0.y);
        a[2] = (short)f2b(u0.z); a[3] = (short)f2b(u0.w);
        a[4] = (short)f2b(u1.x); a[5] = (short)f2b(u1.y);
        a[6] = (short)f2b(u1.z); a[7] = (short)f2b(u1.w);
        afrag[mt][kb] = a;
      }
    } else {
      const unsigned short* xp = (const unsigned short*)xraw + (size_t)nc * 128 + quad * 8;
      #pragma unroll
      for (int kb = 0; kb < 4; ++kb)
        afrag[mt][kb] = *(const bf8_t*)(xp + kb * 32);
    }
  }
  #pragma unroll
  for (int ct = 0; ct < 8; ++ct) {
    bf8_t bfrag[4];
    #pragma unroll
    for (int kb = 0; kb < 4; ++kb)
      bfrag[kb] = *(const bf8_t*)(Wf + ((ct * 4 + kb) * 64 + l) * 8);
    #pragma unroll
    for (int mt = 0; mt < 2; ++mt) {
      f4_t acc = {0.f, 0.f, 0.f, 0.f};
      #pragma unroll
      for (int kb = 0; kb < 4; ++kb)
        acc = __builtin_amdgcn_mfma_f32_16x16x32_bf16(afrag[mt][kb], bfrag[kb], acc, 0, 0, 0);
      #pragma unroll
      for (int r = 0; r < 4; ++r) {
        int node = m0 + mt * 16 + quad * 4 + r;
        if (node < n)
          H[(size_t)node * 128 + ct * 16 + r16] = f2b(acc[r]);
      }
    }
  }
}

// Standalone GEMM: H[n,FOUT] = X[n,FIN] @ Wf (fragment-major). No LDS.
template<int FIN, int FOUT>
__global__ __launch_bounds__(256) void mfma_gemm_kernel(const unsigned short* __restrict__ X,
    const unsigned short* __restrict__ Wf, unsigned short* __restrict__ H, int n) {
  constexpr int KB = FIN / 32;
  constexpr int CT = FOUT / 16;
  const int l = threadIdx.x & 63;
  const int r16 = l & 15, quad = l >> 4;
  const int m0 = (blockIdx.x * 4 + (threadIdx.x >> 6)) * 32;
  if (m0 >= n) return;
  bf8_t afrag[2][KB];
  #pragma unroll
  for (int mt = 0; mt < 2; ++mt) {
    int node = m0 + mt * 16 + r16;
    int nc = node < n ? node : n - 1;
    const unsigned short* xp = X + (size_t)nc * FIN + quad * 8;
    #pragma unroll
    for (int kb = 0; kb < KB; ++kb)
      afrag[mt][kb] = *(const bf8_t*)(xp + kb * 32);
  }
  #pragma unroll
  for (int ct = 0; ct < CT; ++ct) {
    bf8_t bfrag[KB];
    #pragma unroll
    for (int kb = 0; kb < KB; ++kb)
      bfrag[kb] = *(const bf8_t*)(Wf + ((ct * KB + kb) * 64 + l) * 8);
    #pragma unroll
    for (int mt = 0; mt < 2; ++mt) {
      f4_t acc = {0.f, 0.f, 0.f, 0.f};
      #pragma unroll
      for (int kb = 0; kb < KB; ++kb)
        acc = __builtin_amdgcn_mfma_f32_16x16x32_bf16(afrag[mt][kb], bfrag[kb], acc, 0, 0, 0);
      #pragma unroll
      for (int r = 0; r < 4; ++r) {
        int node = m0 + mt * 16 + quad * 4 + r;
        if (node < n)
          H[(size_t)node * FOUT + ct * 16 + r16] = f2b(acc[r]);
      }
    }
  }
}

// ---- generic per-lane vector of DW dwords ----
template<int DW> struct UVec { unsigned int d[DW]; };
template<int DW>
__device__ __forceinline__ UVec<DW> uload(const unsigned int* p) {
  UVec<DW> r;
  if constexpr (DW == 4) { uint4 v = *(const uint4*)p; r.d[0]=v.x; r.d[1]=v.y; r.d[2]=v.z; r.d[3]=v.w; }
  else if constexpr (DW == 2) { uint2 v = *(const uint2*)p; r.d[0]=v.x; r.d[1]=v.y; }
  else { r.d[0] = *p; }
  return r;
}
template<int DW>
__device__ __forceinline__ void ustore(unsigned int* p, const UVec<DW>& v) {
  if constexpr (DW == 4) { *(uint4*)p = make_uint4(v.d[0], v.d[1], v.d[2], v.d[3]); }
  else if constexpr (DW == 2) { *(uint2*)p = make_uint2(v.d[0], v.d[1]); }
  else { *p = v.d[0]; }
}

// Standalone agg: OUT[g,:] = relu(sum coef*H[src] + dinv^2*H[g] + bias).
// LPG lanes/node, F/LPG feats (= DW dwords) per lane. Chain = ceil(deg/LPG).
template<int F, int LPG>
__global__ __launch_bounds__(256) void agg_kernel(const unsigned short* __restrict__ H,
    const int* __restrict__ row_ptr, const uint2* __restrict__ csr,
    const float* __restrict__ dinv,
    const unsigned short* __restrict__ bias, unsigned short* __restrict__ OUT, int n) {
  constexpr int DW = F / LPG / 2;
  constexpr int GPB = 256 / LPG;
  const int g = blockIdx.x * GPB + threadIdx.x / LPG;
  const int l = threadIdx.x % LPG;
  if (g >= n) return;
  const unsigned int* H2 = (const unsigned int*)H;
  float di = dinv[g];
  float c0 = di * di;
  float a[2 * DW];
  {
    UVec<DW> hv = uload<DW>(H2 + (size_t)g * (F / 2) + l * DW);
    #pragma unroll
    for (int d = 0; d < DW; ++d) {
      a[2*d]   = b2f(hv.d[d] & 0xffffu) * c0;
      a[2*d+1] = b2f(hv.d[d] >> 16) * c0;
    }
  }
  const int e0 = row_ptr[g], e1 = row_ptr[g + 1];
  for (int base = e0; base < e1; base += LPG) {
    int cnt = e1 - base < LPG ? e1 - base : LPG;
    uint2 my = csr[(base + l < e1) ? (base + l) : (e1 - 1)];
    for (int j = 0; j < cnt; ++j) {
      int s = __shfl((int)my.x, j, LPG);
      float c = __uint_as_float(__shfl((int)my.y, j, LPG));
      UVec<DW> v = uload<DW>(H2 + (size_t)s * (F / 2) + l * DW);
      #pragma unroll
      for (int d = 0; d < DW; ++d) {
        a[2*d]   = fmaf(b2f(v.d[d] & 0xffffu), c, a[2*d]);
        a[2*d+1] = fmaf(b2f(v.d[d] >> 16), c, a[2*d+1]);
      }
    }
  }
  UVec<DW> bb = uload<DW>((const unsigned int*)bias + l * DW);
  UVec<DW> o;
  #pragma unroll
  for (int d = 0; d < DW; ++d) {
    float lo = fmaxf(a[2*d]   + b2f(bb.d[d] & 0xffffu), 0.f);
    float hi = fmaxf(a[2*d+1] + b2f(bb.d[d] >> 16), 0.f);
    o.d[d] = (unsigned int)f2b(lo) | ((unsigned int)f2b(hi) << 16);
  }
  ustore<DW>((unsigned int*)OUT + (size_t)g * (F / 2) + l * DW, o);
}

// Fused last-layer agg + mean-pool. LPG=8 lanes/node (2 feats/lane), 32
// nodes/block, grid=(N+31)/32. No device fences (separate final kernel).
__global__ __launch_bounds__(256) void agg_pool_kernel(
    const unsigned short* __restrict__ Hin,
    const int* __restrict__ row_ptr, const uint2* __restrict__ csr,
    const float* __restrict__ dinv, const unsigned short* __restrict__ bias,
    const int* __restrict__ batch, float* __restrict__ pooled,
    float* __restrict__ cnt, int n) {
  __shared__ float acc[N_GRAPHS * 16];
  __shared__ float ccnt[N_GRAPHS];
  for (int i = threadIdx.x; i < N_GRAPHS * 16; i += 256) acc[i] = 0.f;
  if (threadIdx.x < N_GRAPHS) ccnt[threadIdx.x] = 0.f;
  __syncthreads();
  const int r = threadIdx.x >> 3, l = threadIdx.x & 7;
  const int g = blockIdx.x * 32 + r;
  if (g < n) {
    const unsigned int* H2 = (const unsigned int*)Hin;
    float di = dinv[g];
    float c0 = di * di;
    unsigned int hv = H2[(size_t)g * 8 + l];
    float a0 = b2f(hv & 0xffffu) * c0;
    float a1 = b2f(hv >> 16) * c0;
    const int e0 = row_ptr[g], e1 = row_ptr[g + 1];
    for (int base = e0; base < e1; base += 8) {
      int cnt2 = e1 - base < 8 ? e1 - base : 8;
      uint2 my = csr[(base + l < e1) ? (base + l) : (e1 - 1)];
      for (int j = 0; j < cnt2; ++j) {
        int s = __shfl((int)my.x, j, 8);
        float c = __uint_as_float(__shfl((int)my.y, j, 8));
        unsigned int v = H2[(size_t)s * 8 + l];
        a0 = fmaf(b2f(v & 0xffffu), c, a0);
        a1 = fmaf(b2f(v >> 16), c, a1);
      }
    }
    unsigned int bb = ((const unsigned int*)bias)[l];
    a0 = fmaxf(a0 + b2f(bb & 0xffffu), 0.f);
    a1 = fmaxf(a1 + b2f(bb >> 16), 0.f);
    int gb = batch[g];
    atomicAdd(&acc[gb * 16 + l * 2 + 0], a0);
    atomicAdd(&acc[gb * 16 + l * 2 + 1], a1);
    if (l == 0) atomicAdd(&ccnt[gb], 1.f);
  }
  __syncthreads();
  for (int i = threadIdx.x; i < N_GRAPHS * 16; i += 256)
    if (acc[i] != 0.f) atomicAdd(&pooled[i], acc[i]);
  if (threadIdx.x < N_GRAPHS && ccnt[threadIdx.x] != 0.f)
    atomicAdd(&cnt[threadIdx.x], ccnt[threadIdx.x]);
}

__global__ __launch_bounds__(256) void final_kernel(const float* __restrict__ pooled,
    const float* __restrict__ cnt, const unsigned short* __restrict__ wc,
    void* __restrict__ out, const unsigned int* __restrict__ xraw) {
  int f32;
  block_detect(xraw, nullptr, &f32, nullptr);
  int id = blockIdx.x * 256 + threadIdx.x;
  if (id >= N_GRAPHS * N_CLASSES) return;
  const unsigned short* Wlin = wc + WOFF[8];
  const unsigned short* blin = wc + WOFF[9];
  int g = id / N_CLASSES, c = id - g * N_CLASSES;
  float inv = 1.0f / fmaxf(cnt[g], 1.0f);
  float a = b2f(blin[c]);
  #pragma unroll
  for (int f = 0; f < 16; ++f)
    a = fmaf(pooled[g * 16 + f] * inv, b2f(Wlin[f * N_CLASSES + c]), a);
  if (f32) ((float*)out)[id] = a;
  else     ((unsigned short*)out)[id] = f2b(a);
}

extern "C" void kernel_launch(void* const* d_in, const int* in_sizes, int n_in,
                              void* d_out, int out_size, void* d_ws, size_t ws_size,
                              hipStream_t stream) {
  const unsigned int* xraw = (const unsigned int*)d_in[0];
  const int* eraw          = (const int*)d_in[1];
  const int* braw          = (const int*)d_in[2];

  const int N = in_sizes[2];
  const int E = in_sizes[1] / 2;

  char* p = (char*)d_ws;
  auto alloc = [&](size_t bytes) -> void* {
    void* r = (void*)p;
    p += (bytes + 255) & ~(size_t)255;
    return r;
  };
  // zero region: deg | pooled | cnt  (single memset)
  char*  zbase    = (char*) alloc((size_t)N * 4 + 8192);
  int*   deg      = (int*)  zbase;
  float* pooled   = (float*)(zbase + (size_t)N * 4);
  float* cntf     = pooled + N_GRAPHS * 16;
  const size_t zbytes = (size_t)N * 4 + (N_GRAPHS * 16 + N_GRAPHS) * 4;

  int*   partials = (int*)  alloc(1024);
  int*   row_ptr  = (int*)  alloc((size_t)(N + 1) * 4);
  int*   cursor   = (int*)  alloc((size_t)N * 4);
  float* dinv     = (float*)alloc((size_t)N * 4);
  int*   batch32  = (int*)  alloc((size_t)N * 4);
  uint2* csr      = (uint2*)alloc((size_t)E * 8);
  unsigned short* wcan  = (unsigned short*)alloc((size_t)WTOTAL * 2);
  unsigned short* hbufA = (unsigned short*)alloc((size_t)N * 128 * 2);
  unsigned short* hbufB = (unsigned short*)alloc((size_t)N * 128 * 2);

  hipMemsetAsync(zbase, 0, zbytes, stream);

  WPtrs wp;
  for (int i = 0; i < 10; ++i) wp.p[i] = d_in[3 + i];

  const int BW = (WTOTAL + 255) / 256;
  const int BB = (N + 255) / 256;
  const int BE = (E + 255) / 256;
  cvt_we_kernel<<<BW + BB + BE, 256, 0, stream>>>(xraw, wp, wcan, braw, batch32,
      eraw, deg, BW, BB, N, E);

  const int nb = (N + 255) / 256;
  scan1_kernel<<<nb, 256, 0, stream>>>(deg, partials, N);
  scan23_kernel<<<nb, 256, 0, stream>>>(deg, partials, row_ptr, cursor, dinv, N, nb);
  fill_kernel<<<BE, 256, 0, stream>>>(eraw, xraw, cursor, dinv, csr, E);

  const unsigned short* W1 = wcan + WOFF[0];
  const unsigned short* b1 = wcan + WOFF[1];
  const unsigned short* W2 = wcan + WOFF[2];
  const unsigned short* b2 = wcan + WOFF[3];
  const unsigned short* W3 = wcan + WOFF[4];
  const unsigned short* b3 = wcan + WOFF[5];
  const unsigned short* W4 = wcan + WOFF[6];
  const unsigned short* b4 = wcan + WOFF[7];

  const int gblocks = ((N + 31) / 32 + 3) / 4;   // == ceil(N/128)

  gemm1_kernel<<<gblocks, 256, 0, stream>>>(xraw, W1, hbufA, N);
  agg_kernel<128, 16><<<(N + 15) / 16, 256, 0, stream>>>(hbufA, row_ptr, csr, dinv, b1, hbufB, N);
  mfma_gemm_kernel<128, 64><<<gblocks, 256, 0, stream>>>(hbufB, W2, hbufA, N);
  agg_kernel<64, 8><<<(N + 31) / 32, 256, 0, stream>>>(hbufA, row_ptr, csr, dinv, b2, hbufB, N);
  mfma_gemm_kernel<64, 32><<<gblocks, 256, 0, stream>>>(hbufB, W3, hbufA, N);
  agg_kernel<32, 8><<<(N + 31) / 32, 256, 0, stream>>>(hbufA, row_ptr, csr, dinv, b3, hbufB, N);
  mfma_gemm_kernel<32, 16><<<gblocks, 256, 0, stream>>>(hbufB, W4, hbufA, N);
  agg_pool_kernel<<<(N + 31) / 32, 256, 0, stream>>>(hbufA, row_ptr, csr, dinv, b4,
      batch32, pooled, cntf, N);

  final_kernel<<<(N_GRAPHS * N_CLASSES + 255) / 256, 256, 0, stream>>>(pooled, cntf, wcan, d_out, xraw);
}

// Round 9
// 240.184 us; speedup vs baseline: 1.2446x; 1.0921x over previous
//
#include <hip/hip_runtime.h>
#include <hip/hip_bf16.h>

// GCN forward, MI355X. Round 9: dispatch-graph collapse.
//   memset(deg|desc|pooled|cnt)   [one region]
//   cvt_we    : W->bf16 canonical (W1..W4 fragment-major) | batch->i32 |
//               degree count straight from raw edges
//   scan      : ONE dispatch, decoupled-lookback (64-bit packed state|value
//               atomics, fence-free; 196 blocks all co-resident)
//   fill_gemm1: block-range split — packed uint2 CSR fill | X@W1 MFMA
//   aggemm x3 : gather+bias+relu at the AGG's grid (16-32 nodes/block,
//               max occupancy) -> 4KB LDS tile -> MFMA next layer in-block
//   agg_pool  : last-layer gather (LPG=8) + LDS graph pool -> atomics
//   final     : 64x16 @ 16x10 linear, dtype-dispatched store
//
// Lessons: R5 — fusing at the GEMM's grid (N/128) craters occupancy to 13%;
// the fix (this round) is fusing at the AGG's grid since gemm rows only
// need their own node's agg output. R7 — no per-block __threadfence in wide
// grids (L2 writeback storm); lookback uses single-location packed atomics
// instead. Agg chain = ceil(deg/LPG); widen LPG for small F.
//
// MFMA 16x16x32_bf16 layouts (verified): A[m=l&15][k=(l>>4)*8+j] (k-contig);
// B frag f at Wf[f*1024 + l*16..+16] = B[kb*32+(l>>4)*8+j][ct*16+(l&15)],
// f=ct*KB+kb; C/D col=l&15, row=(l>>4)*4+reg.

#define N_GRAPHS 64
#define N_CLASSES 10

typedef short bf8_t __attribute__((ext_vector_type(8)));
typedef float f4_t  __attribute__((ext_vector_type(4)));

__device__ __forceinline__ float b2f(unsigned int u) {
  return __uint_as_float(u << 16);
}
__device__ __forceinline__ unsigned short f2b(float f) {
  unsigned int x = __float_as_uint(f);
  x += 0x7fffu + ((x >> 16) & 1u);   // RNE (finite values only)
  return (unsigned short)(x >> 16);
}

// Per-block dtype detect; call with all 256 threads pre-divergence.
__device__ __forceinline__ void block_detect(const unsigned int* __restrict__ xraw,
    const unsigned int* __restrict__ eraw, int* f32, int* i64) {
  __shared__ int c_bf, c_nz;
  if (threadIdx.x == 0) { c_bf = 0; c_nz = 0; }
  __syncthreads();
  unsigned int d = xraw[threadIdx.x & 255];
  int e = (int)(((d & 0xffffu) >> 7) & 0xff);
  if (e >= 100 && e <= 140) atomicAdd(&c_bf, 1);
  if (eraw && threadIdx.x < 64 && eraw[2 * threadIdx.x + 1] != 0u) atomicAdd(&c_nz, 1);
  __syncthreads();
  *f32 = (c_bf < 150) ? 1 : 0;
  if (i64) *i64 = (c_nz == 0) ? 1 : 0;
}

struct WPtrs { const void* p[10]; };
static constexpr int WSEG[10] = {16384, 128, 8192, 64, 2048, 32, 512, 16, 160, 10};
static constexpr int WTOTAL   = 27546;
static constexpr int WOFF[10] = {0, 16384, 16512, 24704, 24768, 26816, 26848, 27360, 27376, 27536};

// blocks [0,BW): weights; [BW,BW+BB): batch; rest: degree count from eraw.
__global__ __launch_bounds__(256) void cvt_we_kernel(
    const unsigned int* __restrict__ xraw, WPtrs wp, unsigned short* __restrict__ wc,
    const int* __restrict__ braw, int* __restrict__ b32,
    const int* __restrict__ eraw, int* __restrict__ deg,
    int BW, int BB, int n, int E) {
  int f32, i64;
  block_detect(xraw, (const unsigned int*)eraw, &f32, &i64);
  const int bid = blockIdx.x;
  if (bid < BW) {
    int i = bid * 256 + threadIdx.x;
    if (i >= WTOTAL) return;
    int off = i, s = 0;
    #pragma unroll
    for (int t = 0; t < 10; ++t) {
      if (s == 0 && off >= WSEG[t]) { off -= WSEG[t]; } else if (s == 0) { s = t + 1; }
    }
    s -= 1;
    int soff = off;
    if ((s & 1) == 0 && s <= 6) {           // W1..W4 -> fragment-major
      int KB, FOUT;
      if (s == 0)      { KB = 4; FOUT = 128; }
      else if (s == 2) { KB = 4; FOUT = 64; }
      else if (s == 4) { KB = 2; FOUT = 32; }
      else             { KB = 1; FOUT = 16; }
      int j = off & 7, l = (off >> 3) & 63, f = off >> 9;
      int ct = f / KB, kb = f - ct * KB;
      int k = kb * 32 + ((l >> 4) << 3) + j;
      int nn = ct * 16 + (l & 15);
      soff = k * FOUT + nn;
    }
    const void* p = wp.p[s];
    wc[WOFF[s] + off] = f32 ? f2b(((const float*)p)[soff])
                            : ((const unsigned short*)p)[soff];
  } else if (bid < BW + BB) {
    int i = (bid - BW) * 256 + threadIdx.x;
    if (i < n) b32[i] = i64 ? braw[2 * i] : braw[i];
  } else {
    int e = (bid - BW - BB) * 256 + threadIdx.x;
    if (e >= E) return;
    int d = i64 ? eraw[2 * (E + e)] : eraw[E + e];
    atomicAdd(&deg[d], 1);
  }
}

// Single-dispatch scan: per-block local scan + decoupled lookback via packed
// (state<<62 | value) 64-bit atomics. state: 1=aggregate, 2=inclusive prefix.
// No fences — value travels inside the same atomic location.
__global__ __launch_bounds__(256) void scan_kernel(const int* __restrict__ deg,
    int* __restrict__ row_ptr, int* __restrict__ cursor, float* __restrict__ dinv,
    unsigned long long* __restrict__ desc, int n) {
  __shared__ int ws[4];
  __shared__ int s_total;
  __shared__ unsigned int s_prev;
  const int b = blockIdx.x, tid = threadIdx.x, lane = tid & 63, wv = tid >> 6;
  const int i = b * 256 + tid;
  int v = (i < n) ? deg[i] : 0;
  int x = v;
  #pragma unroll
  for (int off = 1; off < 64; off <<= 1) {
    int y = __shfl_up(x, off, 64);
    if (lane >= off) x += y;
  }
  if (lane == 63) ws[wv] = x;
  __syncthreads();
  int wbase = 0;
  for (int w = 0; w < wv; ++w) wbase += ws[w];
  int incl = x + wbase;
  if (tid == 0) {
    int tot = ws[0] + ws[1] + ws[2] + ws[3];
    s_total = tot;
    unsigned long long st = (b == 0) ? (2ULL << 62) : (1ULL << 62);
    atomicExch(&desc[b], st | (unsigned long long)(unsigned int)tot);
    if (b == 0) s_prev = 0u;
  }
  __syncthreads();
  if (b > 0 && wv == 0) {
    unsigned int running = 0;
    int j = b - 1;
    while (true) {
      int idx = j - lane;
      unsigned long long d;
      if (idx >= 0) {
        do { d = atomicAdd(&desc[idx], 0ULL); } while ((d >> 62) == 0ULL);
      } else {
        d = (2ULL << 62);
      }
      unsigned long long ball = __ballot((d >> 62) == 2ULL);
      int fp = ball ? (__ffsll((unsigned long long)ball) - 1) : 64;
      unsigned int contrib = (lane <= fp) ? (unsigned int)(d & 0xffffffffULL) : 0u;
      #pragma unroll
      for (int o = 32; o; o >>= 1) contrib += __shfl_xor(contrib, o, 64);
      running += contrib;
      if (fp < 64) break;
      j -= 64;
    }
    if (lane == 0) {
      atomicExch(&desc[b], (2ULL << 62) |
                 (unsigned long long)(unsigned int)(running + (unsigned int)s_total));
      s_prev = running;
    }
  }
  __syncthreads();
  int tot = (int)s_prev + incl;
  if (i < n) {
    row_ptr[i + 1] = tot;
    cursor[i] = tot - v;
    dinv[i] = rsqrtf((float)v + 1.0f);
  }
  if (i == 0) row_ptr[0] = 0;
}

// Merged: blocks [0,BE) fill packed CSR from raw edges; rest X@W1 via MFMA.
__global__ __launch_bounds__(256) void fill_gemm1_kernel(
    const int* __restrict__ eraw, const unsigned int* __restrict__ xraw,
    int* __restrict__ cursor, const float* __restrict__ dinv,
    uint2* __restrict__ csr,
    const unsigned short* __restrict__ Wf, unsigned short* __restrict__ H,
    int BE, int n, int E) {
  int f32, i64;
  block_detect(xraw, (const unsigned int*)eraw, &f32, &i64);
  if (blockIdx.x < BE) {
    int e = blockIdx.x * 256 + threadIdx.x;
    if (e < E) {
      int s, d;
      if (i64) { s = eraw[2 * e]; d = eraw[2 * (E + e)]; }
      else     { s = eraw[e];     d = eraw[E + e]; }
      int pos = atomicAdd(&cursor[d], 1);
      uint2 v;
      v.x = (unsigned int)s;
      v.y = __float_as_uint(dinv[s] * dinv[d]);
      csr[pos] = v;
    }
    return;
  }
  const int b2 = blockIdx.x - BE;
  const int l = threadIdx.x & 63;
  const int r16 = l & 15, quad = l >> 4;
  const int m0 = (b2 * 4 + (threadIdx.x >> 6)) * 32;
  if (m0 >= n) return;
  bf8_t afrag[2][4];
  #pragma unroll
  for (int mt = 0; mt < 2; ++mt) {
    int node = m0 + mt * 16 + r16;
    int nc = node < n ? node : n - 1;
    if (f32) {
      const float* xp = (const float*)xraw + (size_t)nc * 128 + quad * 8;
      #pragma unroll
      for (int kb = 0; kb < 4; ++kb) {
        const float4* p4 = (const float4*)(xp + kb * 32);
        float4 u0 = p4[0], u1 = p4[1];
        bf8_t a;
        a[0] = (short)f2b(u0.x); a[1] = (short)f2b(u0.y);
        a[2] = (short)f2b(u0.z); a[3] = (short)f2b(u0.w);
        a[4] = (short)f2b(u1.x); a[5] = (short)f2b(u1.y);
        a[6] = (short)f2b(u1.z); a[7] = (short)f2b(u1.w);
        afrag[mt][kb] = a;
      }
    } else {
      const unsigned short* xp = (const unsigned short*)xraw + (size_t)nc * 128 + quad * 8;
      #pragma unroll
      for (int kb = 0; kb < 4; ++kb)
        afrag[mt][kb] = *(const bf8_t*)(xp + kb * 32);
    }
  }
  #pragma unroll
  for (int ct = 0; ct < 8; ++ct) {
    bf8_t bfrag[4];
    #pragma unroll
    for (int kb = 0; kb < 4; ++kb)
      bfrag[kb] = *(const bf8_t*)(Wf + ((ct * 4 + kb) * 64 + l) * 8);
    #pragma unroll
    for (int mt = 0; mt < 2; ++mt) {
      f4_t acc = {0.f, 0.f, 0.f, 0.f};
      #pragma unroll
      for (int kb = 0; kb < 4; ++kb)
        acc = __builtin_amdgcn_mfma_f32_16x16x32_bf16(afrag[mt][kb], bfrag[kb], acc, 0, 0, 0);
      #pragma unroll
      for (int r = 0; r < 4; ++r) {
        int node = m0 + mt * 16 + quad * 4 + r;
        if (node < n)
          H[(size_t)node * 128 + ct * 16 + r16] = f2b(acc[r]);
      }
    }
  }
}

// ---- generic per-lane vector of DW dwords ----
template<int DW> struct UVec { unsigned int d[DW]; };
template<int DW>
__device__ __forceinline__ UVec<DW> uload(const unsigned int* p) {
  UVec<DW> r;
  if constexpr (DW == 4) { uint4 v = *(const uint4*)p; r.d[0]=v.x; r.d[1]=v.y; r.d[2]=v.z; r.d[3]=v.w; }
  else if constexpr (DW == 2) { uint2 v = *(const uint2*)p; r.d[0]=v.x; r.d[1]=v.y; }
  else { r.d[0] = *p; }
  return r;
}
template<int DW>
__device__ __forceinline__ void ustore(unsigned int* p, const UVec<DW>& v) {
  if constexpr (DW == 4) { *(uint4*)p = make_uint4(v.d[0], v.d[1], v.d[2], v.d[3]); }
  else if constexpr (DW == 2) { *(uint2*)p = make_uint2(v.d[0], v.d[1]); }
  else { *p = v.d[0]; }
}

// Fused agg(FIN, bias, relu) -> LDS tile -> MFMA @ Wf(FIN x FOUT) -> Hout.
// Grid = agg's grid (NPB=256/LPG nodes per block) so occupancy is preserved
// (R5 lesson). Gemm rows only need their own node's agg output.
template<int FIN, int FOUT, int LPG>
__global__ __launch_bounds__(256) void aggemm_kernel(
    const unsigned short* __restrict__ Hin,
    const int* __restrict__ row_ptr, const uint2* __restrict__ csr,
    const float* __restrict__ dinv, const unsigned short* __restrict__ bias,
    const unsigned short* __restrict__ Wf, unsigned short* __restrict__ Hout, int n) {
  constexpr int DW  = FIN / LPG / 2;     // dwords per lane
  constexpr int NPB = 256 / LPG;         // nodes per block (16 or 32)
  constexpr int LD  = FIN + 8;           // LDS row pitch in shorts
  constexpr int KB  = FIN / 32;
  constexpr int CT  = FOUT / 16;
  constexpr int MT  = NPB / 16;
  __shared__ unsigned short T[NPB * LD];
  const int r = threadIdx.x / LPG, l = threadIdx.x % LPG;
  const int node0 = blockIdx.x * NPB;
  const int g = node0 + r;
  const unsigned int* H2 = (const unsigned int*)Hin;
  UVec<DW> o;
  #pragma unroll
  for (int d = 0; d < DW; ++d) o.d[d] = 0u;
  if (g < n) {
    float di = dinv[g];
    float c0 = di * di;
    float a[2 * DW];
    UVec<DW> hv = uload<DW>(H2 + (size_t)g * (FIN / 2) + l * DW);
    #pragma unroll
    for (int d = 0; d < DW; ++d) {
      a[2*d]   = b2f(hv.d[d] & 0xffffu) * c0;
      a[2*d+1] = b2f(hv.d[d] >> 16) * c0;
    }
    const int e0 = row_ptr[g], e1 = row_ptr[g + 1];
    for (int base = e0; base < e1; base += LPG) {
      int cnt = e1 - base < LPG ? e1 - base : LPG;
      uint2 my = csr[(base + l < e1) ? (base + l) : (e1 - 1)];
      for (int j = 0; j < cnt; ++j) {
        int s = __shfl((int)my.x, j, LPG);
        float c = __uint_as_float(__shfl((int)my.y, j, LPG));
        UVec<DW> v = uload<DW>(H2 + (size_t)s * (FIN / 2) + l * DW);
        #pragma unroll
        for (int d = 0; d < DW; ++d) {
          a[2*d]   = fmaf(b2f(v.d[d] & 0xffffu), c, a[2*d]);
          a[2*d+1] = fmaf(b2f(v.d[d] >> 16), c, a[2*d+1]);
        }
      }
    }
    UVec<DW> bb = uload<DW>((const unsigned int*)bias + l * DW);
    #pragma unroll
    for (int d = 0; d < DW; ++d) {
      float lo = fmaxf(a[2*d]   + b2f(bb.d[d] & 0xffffu), 0.f);
      float hi = fmaxf(a[2*d+1] + b2f(bb.d[d] >> 16), 0.f);
      o.d[d] = (unsigned int)f2b(lo) | ((unsigned int)f2b(hi) << 16);
    }
  }
  ustore<DW>((unsigned int*)&T[r * LD + l * DW * 2], o);
  __syncthreads();
  // ---- MFMA phase: wave w covers (mt, ct) combo ----
  const int w = threadIdx.x >> 6;
  if (w < MT * CT && node0 < n) {
    const int mt = w / CT, ct = w % CT;
    const int ll = threadIdx.x & 63;
    const int r16 = ll & 15, quad = ll >> 4;
    bf8_t afrag[KB], bfrag[KB];
    #pragma unroll
    for (int kb = 0; kb < KB; ++kb) {
      afrag[kb] = *(const bf8_t*)(&T[(mt * 16 + r16) * LD + quad * 8 + kb * 32]);
      bfrag[kb] = *(const bf8_t*)(Wf + ((ct * KB + kb) * 64 + ll) * 8);
    }
    f4_t acc = {0.f, 0.f, 0.f, 0.f};
    #pragma unroll
    for (int kb = 0; kb < KB; ++kb)
      acc = __builtin_amdgcn_mfma_f32_16x16x32_bf16(afrag[kb], bfrag[kb], acc, 0, 0, 0);
    #pragma unroll
    for (int rr = 0; rr < 4; ++rr) {
      int node = node0 + mt * 16 + quad * 4 + rr;
      if (node < n)
        Hout[(size_t)node * FOUT + ct * 16 + r16] = f2b(acc[rr]);
    }
  }
}

// Fused last-layer agg + mean-pool. LPG=8, 32 nodes/block.
__global__ __launch_bounds__(256) void agg_pool_kernel(
    const unsigned short* __restrict__ Hin,
    const int* __restrict__ row_ptr, const uint2* __restrict__ csr,
    const float* __restrict__ dinv, const unsigned short* __restrict__ bias,
    const int* __restrict__ batch, float* __restrict__ pooled,
    float* __restrict__ cnt, int n) {
  __shared__ float acc[N_GRAPHS * 16];
  __shared__ float ccnt[N_GRAPHS];
  for (int i = threadIdx.x; i < N_GRAPHS * 16; i += 256) acc[i] = 0.f;
  if (threadIdx.x < N_GRAPHS) ccnt[threadIdx.x] = 0.f;
  __syncthreads();
  const int r = threadIdx.x >> 3, l = threadIdx.x & 7;
  const int g = blockIdx.x * 32 + r;
  if (g < n) {
    const unsigned int* H2 = (const unsigned int*)Hin;
    float di = dinv[g];
    float c0 = di * di;
    unsigned int hv = H2[(size_t)g * 8 + l];
    float a0 = b2f(hv & 0xffffu) * c0;
    float a1 = b2f(hv >> 16) * c0;
    const int e0 = row_ptr[g], e1 = row_ptr[g + 1];
    for (int base = e0; base < e1; base += 8) {
      int cnt2 = e1 - base < 8 ? e1 - base : 8;
      uint2 my = csr[(base + l < e1) ? (base + l) : (e1 - 1)];
      for (int j = 0; j < cnt2; ++j) {
        int s = __shfl((int)my.x, j, 8);
        float c = __uint_as_float(__shfl((int)my.y, j, 8));
        unsigned int v = H2[(size_t)s * 8 + l];
        a0 = fmaf(b2f(v & 0xffffu), c, a0);
        a1 = fmaf(b2f(v >> 16), c, a1);
      }
    }
    unsigned int bb = ((const unsigned int*)bias)[l];
    a0 = fmaxf(a0 + b2f(bb & 0xffffu), 0.f);
    a1 = fmaxf(a1 + b2f(bb >> 16), 0.f);
    int gb = batch[g];
    atomicAdd(&acc[gb * 16 + l * 2 + 0], a0);
    atomicAdd(&acc[gb * 16 + l * 2 + 1], a1);
    if (l == 0) atomicAdd(&ccnt[gb], 1.f);
  }
  __syncthreads();
  for (int i = threadIdx.x; i < N_GRAPHS * 16; i += 256)
    if (acc[i] != 0.f) atomicAdd(&pooled[i], acc[i]);
  if (threadIdx.x < N_GRAPHS && ccnt[threadIdx.x] != 0.f)
    atomicAdd(&cnt[threadIdx.x], ccnt[threadIdx.x]);
}

__global__ __launch_bounds__(256) void final_kernel(const float* __restrict__ pooled,
    const float* __restrict__ cnt, const unsigned short* __restrict__ wc,
    void* __restrict__ out, const unsigned int* __restrict__ xraw) {
  int f32;
  block_detect(xraw, nullptr, &f32, nullptr);
  int id = blockIdx.x * 256 + threadIdx.x;
  if (id >= N_GRAPHS * N_CLASSES) return;
  const unsigned short* Wlin = wc + WOFF[8];
  const unsigned short* blin = wc + WOFF[9];
  int g = id / N_CLASSES, c = id - g * N_CLASSES;
  float inv = 1.0f / fmaxf(cnt[g], 1.0f);
  float a = b2f(blin[c]);
  #pragma unroll
  for (int f = 0; f < 16; ++f)
    a = fmaf(pooled[g * 16 + f] * inv, b2f(Wlin[f * N_CLASSES + c]), a);
  if (f32) ((float*)out)[id] = a;
  else     ((unsigned short*)out)[id] = f2b(a);
}

extern "C" void kernel_launch(void* const* d_in, const int* in_sizes, int n_in,
                              void* d_out, int out_size, void* d_ws, size_t ws_size,
                              hipStream_t stream) {
  const unsigned int* xraw = (const unsigned int*)d_in[0];
  const int* eraw          = (const int*)d_in[1];
  const int* braw          = (const int*)d_in[2];

  const int N = in_sizes[2];
  const int E = in_sizes[1] / 2;
  const int nb = (N + 255) / 256;

  char* p = (char*)d_ws;
  auto alloc = [&](size_t bytes) -> void* {
    void* r = (void*)p;
    p += (bytes + 255) & ~(size_t)255;
    return r;
  };
  // zero region: deg | desc | pooled | cnt  (single memset)
  const size_t off_desc = ((size_t)N * 4 + 255) & ~(size_t)255;
  const size_t off_pool = (off_desc + (size_t)nb * 8 + 255) & ~(size_t)255;
  const size_t ztotal   = off_pool + (N_GRAPHS * 16 + N_GRAPHS) * 4;
  char* zbase = (char*)alloc(ztotal);
  int*   deg    = (int*)zbase;
  unsigned long long* desc = (unsigned long long*)(zbase + off_desc);
  float* pooled = (float*)(zbase + off_pool);
  float* cntf   = pooled + N_GRAPHS * 16;

  int*   row_ptr  = (int*)  alloc((size_t)(N + 1) * 4);
  int*   cursor   = (int*)  alloc((size_t)N * 4);
  float* dinv     = (float*)alloc((size_t)N * 4);
  int*   batch32  = (int*)  alloc((size_t)N * 4);
  uint2* csr      = (uint2*)alloc((size_t)E * 8);
  unsigned short* wcan  = (unsigned short*)alloc((size_t)WTOTAL * 2);
  unsigned short* hbufA = (unsigned short*)alloc((size_t)N * 128 * 2);
  unsigned short* hbufB = (unsigned short*)alloc((size_t)N * 128 * 2);

  hipMemsetAsync(zbase, 0, ztotal, stream);

  WPtrs wp;
  for (int i = 0; i < 10; ++i) wp.p[i] = d_in[3 + i];

  const int BW = (WTOTAL + 255) / 256;
  const int BB = nb;
  const int BE = (E + 255) / 256;
  cvt_we_kernel<<<BW + BB + BE, 256, 0, stream>>>(xraw, wp, wcan, braw, batch32,
      eraw, deg, BW, BB, N, E);

  scan_kernel<<<nb, 256, 0, stream>>>(deg, row_ptr, cursor, dinv, desc, N);

  const unsigned short* W1 = wcan + WOFF[0];
  const unsigned short* b1 = wcan + WOFF[1];
  const unsigned short* W2 = wcan + WOFF[2];
  const unsigned short* b2 = wcan + WOFF[3];
  const unsigned short* W3 = wcan + WOFF[4];
  const unsigned short* b3 = wcan + WOFF[5];
  const unsigned short* W4 = wcan + WOFF[6];
  const unsigned short* b4 = wcan + WOFF[7];

  const int G1 = (N + 127) / 128;
  fill_gemm1_kernel<<<BE + G1, 256, 0, stream>>>(eraw, xraw, cursor, dinv, csr,
      W1, hbufA, BE, N, E);

  aggemm_kernel<128, 64, 16><<<(N + 15) / 16, 256, 0, stream>>>(
      hbufA, row_ptr, csr, dinv, b1, W2, hbufB, N);
  aggemm_kernel<64, 32, 8><<<(N + 31) / 32, 256, 0, stream>>>(
      hbufB, row_ptr, csr, dinv, b2, W3, hbufA, N);
  aggemm_kernel<32, 16, 8><<<(N + 31) / 32, 256, 0, stream>>>(
      hbufA, row_ptr, csr, dinv, b3, W4, hbufB, N);
  agg_pool_kernel<<<(N + 31) / 32, 256, 0, stream>>>(hbufB, row_ptr, csr, dinv, b4,
      batch32, pooled, cntf, N);

  final_kernel<<<(N_GRAPHS * N_CLASSES + 255) / 256, 256, 0, stream>>>(pooled, cntf, wcan, d_out, xraw);
}